// Round 4
// baseline (94.739 us; speedup 1.0000x reference)
//
#include <hip/hip_runtime.h>

#define CHPB  10      // channels per block
#define BLOCK 256
#define ROWS  25      // output rows per channel (one thread each)

// search: [N][32][32], kernel: [N][8][8], out: [N][25][25], N = B*C = 32768
__global__ __launch_bounds__(BLOCK, 2) void dwxcorr_kernel(
    const float* __restrict__ kern,
    const float* __restrict__ srch,
    float* __restrict__ out,
    int nch)
{
    __shared__ float s_s[CHPB * 1024];  // search tiles, 16B-chunk XOR-swizzled by row
    __shared__ float s_k[CHPB * 64];    // kernel tiles, linear

    const int tid = threadIdx.x;
    const int ch0 = blockIdx.x * CHPB;
    const int nch_blk = min(CHPB, nch - ch0);

    // ---- stage search tiles (coalesced float4, swizzled LDS dest) ----
    {
        const float4* g = (const float4*)(srch + (size_t)ch0 * 1024);
        const int total = nch_blk * 256;          // float4 count
        for (int idx = tid; idx < total; idx += BLOCK) {
            float4 v = g[idx];
            int ch    = idx >> 8;                 // / 256
            int e4    = idx & 255;                // float4 within channel
            int row   = e4 >> 3;                  // 8 chunks per 32-float row
            int chunk = e4 & 7;
            int sw    = chunk ^ (row & 7);        // bank-decorrelating swizzle
            *(float4*)&s_s[ch * 1024 + row * 32 + sw * 4] = v;
        }
    }
    // ---- stage kernel tiles (linear) ----
    {
        const float4* g = (const float4*)(kern + (size_t)ch0 * 64);
        const int total = nch_blk * 16;
        for (int idx = tid; idx < total; idx += BLOCK) {
            ((float4*)s_k)[idx] = g[idx];
        }
    }
    __syncthreads();

    const int ch_l = tid / ROWS;   // local channel 0..10
    const int i    = tid % ROWS;   // output row
    if (ch_l < nch_blk) {
        float acc[25];
        #pragma unroll
        for (int o = 0; o < 25; ++o) acc[o] = 0.0f;

        const float* sbase = &s_s[ch_l * 1024];
        const float* kbase = &s_k[ch_l * 64];

        for (int u = 0; u < 8; ++u) {
            const int row = i + u;

            // kernel row u: 8 floats (broadcast across the channel's threads)
            float kr[8];
            #pragma unroll
            for (int c2 = 0; c2 < 2; ++c2) {
                float4 kv = *(const float4*)&kbase[u * 8 + c2 * 4];
                kr[c2*4+0] = kv.x; kr[c2*4+1] = kv.y;
                kr[c2*4+2] = kv.z; kr[c2*4+3] = kv.w;
            }

            // full 32-float search row into registers (8x ds_read_b128, de-swizzled)
            float srow[32];
            #pragma unroll
            for (int c = 0; c < 8; ++c) {
                int sw = c ^ (row & 7);
                float4 sv = *(const float4*)&sbase[row * 32 + sw * 4];
                srow[c*4+0] = sv.x; srow[c*4+1] = sv.y;
                srow[c*4+2] = sv.z; srow[c*4+3] = sv.w;
            }

            // 8 taps x 25 outputs = 200 FMAs, all register operands
            #pragma unroll
            for (int v = 0; v < 8; ++v) {
                #pragma unroll
                for (int o = 0; o < 25; ++o) {
                    acc[o] = fmaf(kr[v], srow[o + v], acc[o]);
                }
            }
        }

        float* op = out + (size_t)(ch0 + ch_l) * 625 + i * 25;
        #pragma unroll
        for (int o = 0; o < 25; ++o) op[o] = acc[o];
    }
}

extern "C" void kernel_launch(void* const* d_in, const int* in_sizes, int n_in,
                              void* d_out, int out_size, void* d_ws, size_t ws_size,
                              hipStream_t stream) {
    const float* kern = (const float*)d_in[0];   // (128,256,8,8)
    const float* srch = (const float*)d_in[1];   // (128,256,32,32)
    float* out = (float*)d_out;                  // (128,256,25,25)

    const int nch = in_sizes[0] / 64;            // B*C = 32768
    const int grid = (nch + CHPB - 1) / CHPB;    // 3277
    dwxcorr_kernel<<<grid, BLOCK, 0, stream>>>(kern, srch, out, nch);
}

// Round 6
// 57.000 us; speedup vs baseline: 1.6621x; 1.6621x over previous
//
#include <hip/hip_runtime.h>

#define BLOCK 256
#define CHPB  8            // channels per block (2 per wave)
#define SROW  33           // padded search row stride (floats): bank = (r+j+v)%32, conflict-free
#define SCH   (32 * SROW)  // 1056 floats per channel

// search: [N][32][32], kernel: [N][8][8], out: [N][25][25], N = B*C = 32768
__global__ __launch_bounds__(BLOCK, 4) void dwxcorr_kernel(
    const float* __restrict__ kern,
    const float* __restrict__ srch,
    float* __restrict__ out,
    int nch)
{
    __shared__ float s_s[CHPB * SCH];   // 33,792 B
    __shared__ float s_k[CHPB * 64];    //  2,048 B  -> 4 blocks/CU

    const int tid = threadIdx.x;
    const int ch0 = blockIdx.x * CHPB;

    // ---- stage search: float4 global loads (coalesced), b32 LDS writes into stride-33 rows ----
    {
        const float4* g = (const float4*)(srch + (size_t)ch0 * 1024);
        #pragma unroll
        for (int it = 0; it < 8; ++it) {
            int e4 = tid + it * BLOCK;            // float4 index, 0..2047
            int ch = e4 >> 8;
            if (ch0 + ch < nch) {
                float4 v = g[e4];
                int rem = e4 & 255;
                int r   = rem >> 3;
                int c   = rem & 7;
                float* dst = &s_s[ch * SCH + r * SROW + c * 4];
                dst[0] = v.x; dst[1] = v.y; dst[2] = v.z; dst[3] = v.w;
            }
        }
    }
    // ---- stage kernel tiles: 8 ch x 64 floats = 128 float4 ----
    if (tid < CHPB * 16) {
        int ch = tid >> 4;
        if (ch0 + ch < nch) {
            const float4* g = (const float4*)(kern + (size_t)ch0 * 64);
            ((float4*)s_k)[tid] = g[tid];
        }
    }
    __syncthreads();

    const int wave = tid >> 6;
    const int lane = tid & 63;
    const int ch_l = wave * 2 + (lane >> 5);   // 2 channels per wave
    const int j    = lane & 31;                // output column (25 active)

    if (j < 25 && ch0 + ch_l < nch) {
        // kernel tile -> 64 registers (broadcast within each half-wave: free)
        float kk[64];
        const float4* kb = (const float4*)&s_k[ch_l * 64];
        #pragma unroll
        for (int w = 0; w < 16; ++w) {
            float4 kv = kb[w];
            kk[w*4+0] = kv.x; kk[w*4+1] = kv.y; kk[w*4+2] = kv.z; kk[w*4+3] = kv.w;
        }

        float acc[25];
        #pragma unroll
        for (int i = 0; i < 25; ++i) acc[i] = 0.0f;

        const float* sb = &s_s[ch_l * SCH + j];

        // loop absolute search row r; each row read once (8 floats), feeds
        // every output row i = r - u that uses it. All indices compile-time.
        #pragma unroll
        for (int r = 0; r < 32; ++r) {
            float sv[8];
            #pragma unroll
            for (int v = 0; v < 8; ++v) sv[v] = sb[r * SROW + v];

            #pragma unroll
            for (int u = 0; u < 8; ++u) {
                if (u >= ((r > 24) ? (r - 24) : 0) && u <= ((r < 7) ? r : 7)) {
                    const int i = r - u;
                    #pragma unroll
                    for (int v = 0; v < 8; ++v)
                        acc[i] = fmaf(kk[u*8 + v], sv[v], acc[i]);
                }
            }
        }

        float* op = out + (size_t)(ch0 + ch_l) * 625 + j;
        #pragma unroll
        for (int i = 0; i < 25; ++i) op[i * 25] = acc[i];
    }
}

extern "C" void kernel_launch(void* const* d_in, const int* in_sizes, int n_in,
                              void* d_out, int out_size, void* d_ws, size_t ws_size,
                              hipStream_t stream) {
    const float* kern = (const float*)d_in[0];   // (128,256,8,8)
    const float* srch = (const float*)d_in[1];   // (128,256,32,32)
    float* out = (float*)d_out;                  // (128,256,25,25)

    const int nch = in_sizes[0] / 64;            // B*C = 32768
    const int grid = (nch + CHPB - 1) / CHPB;    // 4096
    dwxcorr_kernel<<<grid, BLOCK, 0, stream>>>(kern, srch, out, nch);
}